// Round 2
// baseline (11.264 us; speedup 1.0000x reference)
//
#include <hip/hip_runtime.h>

// MiniBatchAUC: loss = sum_{i in pos, j in neg} (1 - (s_i - s_j))^2 / (n_pos*n_neg),
// s = sigmoid(logits). Closed form in 6 O(N) reductions:
//   loss_total = np*nn - 2*nn*Sp + 2*np*Sn + nn*Sp2 + np*Sn2 - 2*Sp*Sn
//
// Round 1 was a single block (one CU) at 10.8 us — latency-bound on one CU.
// Now: k1 = 64 blocks x 64 threads (4096 threads, one float4/int4 each,
// spread across 64 CUs), partials -> d_ws; k2 = one wave combining 64x6
// partials in double via butterfly shuffle. Deterministic (fixed reduce order).

#define G1 64   // blocks in kernel 1 (one wave each)
#define B1 64   // threads per block (exactly one wave)

__global__ __launch_bounds__(B1) void auc_partial_kernel(
    const float* __restrict__ logits, const int* __restrict__ targets,
    float* __restrict__ ws, int n) {
  const int gtid = blockIdx.x * B1 + threadIdx.x;
  const int nthreads = G1 * B1;

  // acc: [0]=n_pos [1]=n_neg [2]=Sp [3]=Sn [4]=Sp2 [5]=Sn2
  float acc[6] = {0.f, 0.f, 0.f, 0.f, 0.f, 0.f};

  const int n4 = n >> 2;
  const float4* l4 = reinterpret_cast<const float4*>(logits);
  const int4*   t4 = reinterpret_cast<const int4*>(targets);

  for (int i = gtid; i < n4; i += nthreads) {  // one iter for N=16384
    float4 lv = l4[i];
    int4   tv = t4[i];
    float xs[4] = {lv.x, lv.y, lv.z, lv.w};
    int   ts[4] = {tv.x, tv.y, tv.z, tv.w};
#pragma unroll
    for (int k = 0; k < 4; ++k) {
      float s  = 1.0f / (1.0f + __expf(-xs[k]));
      float s2 = s * s;
      float p  = (ts[k] != 0) ? 1.0f : 0.0f;
      float q  = 1.0f - p;
      acc[0] += p;       acc[1] += q;
      acc[2] += p * s;   acc[3] += q * s;
      acc[4] += p * s2;  acc[5] += q * s2;
    }
  }
  // scalar tail for n % 4 != 0 (not hit at N=16384)
  for (int i = (n4 << 2) + gtid; i < n; i += nthreads) {
    float s  = 1.0f / (1.0f + __expf(-logits[i]));
    float s2 = s * s;
    float p  = (targets[i] != 0) ? 1.0f : 0.0f;
    float q  = 1.0f - p;
    acc[0] += p;       acc[1] += q;
    acc[2] += p * s;   acc[3] += q * s;
    acc[4] += p * s2;  acc[5] += q * s2;
  }

  // wave-64 butterfly reduce (block == one wave)
#pragma unroll
  for (int j = 0; j < 6; ++j) {
#pragma unroll
    for (int m = 1; m < 64; m <<= 1) {
      acc[j] += __shfl_xor(acc[j], m, 64);
    }
  }

  if (threadIdx.x == 0) {
#pragma unroll
    for (int j = 0; j < 6; ++j) ws[blockIdx.x * 6 + j] = acc[j];
  }
}

__global__ __launch_bounds__(64) void auc_combine_kernel(
    const float* __restrict__ ws, float* __restrict__ out) {
  const int lane = threadIdx.x;  // 0..63, one partial-set per lane

  double t[6];
#pragma unroll
  for (int j = 0; j < 6; ++j) t[j] = (double)ws[lane * 6 + j];

  // butterfly reduce in double across the wave (fixed order -> deterministic)
#pragma unroll
  for (int j = 0; j < 6; ++j) {
#pragma unroll
    for (int m = 1; m < 64; m <<= 1) {
      t[j] += __shfl_xor(t[j], m, 64);
    }
  }

  if (lane == 0) {
    double np_ = t[0], nn = t[1], sp = t[2], sn = t[3], sp2 = t[4], sn2 = t[5];
    double loss = np_ * nn
                - 2.0 * nn * sp
                + 2.0 * np_ * sn
                + nn * sp2
                + np_ * sn2
                - 2.0 * sp * sn;
    out[0] = (float)(loss / (np_ * nn));
  }
}

extern "C" void kernel_launch(void* const* d_in, const int* in_sizes, int n_in,
                              void* d_out, int out_size, void* d_ws, size_t ws_size,
                              hipStream_t stream) {
  const float* logits  = (const float*)d_in[0];
  const int*   targets = (const int*)d_in[1];
  float*       out     = (float*)d_out;
  float*       ws      = (float*)d_ws;   // needs G1*6 floats = 1.5 KB
  const int n = in_sizes[0];

  auc_partial_kernel<<<dim3(G1), dim3(B1), 0, stream>>>(logits, targets, ws, n);
  auc_combine_kernel<<<dim3(1), dim3(64), 0, stream>>>(ws, out);
}